// Round 3
// baseline (2751.047 us; speedup 1.0000x reference)
//
#include <hip/hip_runtime.h>
#include <hip/hip_fp16.h>

#define NB 64
#define NT 512
#define ND 128
#define NH 256
#define G4 1024                     // 4*H
#define NBT (NB*NT)                 // 32768
#define CSTRIDE ((size_t)NBT * G4)  // elements per interval component of px
#define OSTRIDE ((size_t)NBT * NH)  // elements per interval component of out

typedef _Float16 f16x2 __attribute__((ext_vector_type(2)));

__device__ __forceinline__ float fdot2u(unsigned a, unsigned b, float c) {
  return __builtin_amdgcn_fdot2(__builtin_bit_cast(f16x2, a),
                                __builtin_bit_cast(f16x2, b), c, false);
}

// val-only: 4 fdot2
__device__ __forceinline__ void accV(uint4 w, uint4 hv, float& av) {
  av = fdot2u(w.x, hv.x, av);
  av = fdot2u(w.y, hv.y, av);
  av = fdot2u(w.z, hv.z, av);
  av = fdot2u(w.w, hv.w, av);
}
// interval: mid += w.hm, rad += |w|.hr
__device__ __forceinline__ void accMR(uint4 w, uint4 hm, uint4 hr, float& am, float& ar) {
  const unsigned M = 0x7FFF7FFFu;
  am = fdot2u(w.x, hm.x, am); ar = fdot2u(w.x & M, hr.x, ar);
  am = fdot2u(w.y, hm.y, am); ar = fdot2u(w.y & M, hr.y, ar);
  am = fdot2u(w.z, hm.z, am); ar = fdot2u(w.z & M, hr.z, ar);
  am = fdot2u(w.w, hm.w, am); ar = fdot2u(w.w & M, hr.w, ar);
}

// quad all-reduce via DPP quad_perm (verified R2-R4)
__device__ __forceinline__ float qsum4(float x) {
  int v = __builtin_amdgcn_update_dpp(0, __builtin_bit_cast(int, x), 0xB1, 0xF, 0xF, true);
  x += __builtin_bit_cast(float, v);
  v = __builtin_amdgcn_update_dpp(0, __builtin_bit_cast(int, x), 0x4E, 0xF, 0xF, true);
  x += __builtin_bit_cast(float, v);
  return x;
}
__device__ __forceinline__ float sel4(float x0, float x1, float x2, float x3, int q) {
  float a = (q & 1) ? x1 : x0;
  float b = (q & 1) ? x3 : x2;
  return (q & 2) ? b : a;
}
// quad broadcast of lane (PAT selects source lane in quad: 0x00/0x55/0xAA/0xFF)
template <int PAT>
__device__ __forceinline__ float qb(float x) {
  return __builtin_bit_cast(float,
      __builtin_amdgcn_update_dpp(0, __builtin_bit_cast(int, x), PAT, 0xF, 0xF, true));
}

__device__ __forceinline__ float rcpf(float x) { return __builtin_amdgcn_rcpf(x); }
__device__ __forceinline__ float gact(float x, bool is_tanh) {
  float s = is_tanh ? -2.0f : -1.0f;
  float e = __expf(s * x);
  float r = rcpf(1.0f + e);
  return is_tanh ? fmaf(2.0f, r, -1.0f) : r;
}
__device__ __forceinline__ float tanh_f(float x) {
  return fmaf(2.0f, rcpf(1.0f + __expf(-2.0f * x)), -1.0f);
}

// Pack weights f32->f16.
// P4 (R7 gate-minor full-K layout):
//   P4[(c<<10) + t] = Whh[j][c*8 .. c*8+7],  j = 256*(t&3) + (t>>2),  c=0..31
//   (c=0..23 VGPR-pinned; c=24..31 LDS)
// PIH (R7 gate-minor row set; K-quarter structure unchanged):
//   PIH[(c*8+r)*512 + t] = Wih[jp][(t&3)*32 + c*8 ..+8],
//   jp = ((r>>1)<<8) + ((t>>2)<<1) + (r&1)
__global__ void conv_w_kernel(const float* __restrict__ Whh, const float* __restrict__ Wih,
                              uint4* __restrict__ P4, uint4* __restrict__ PIH) {
  int o = blockIdx.x * 256 + threadIdx.x;
  union { uint4 u; __half h[8]; } p;
  if (o < 32768) {
    int t = o & 1023, c = o >> 10;
    int j = ((t & 3) << 8) + (t >> 2), k = c * 8;
    const float* s = Whh + j * NH + k;
#pragma unroll
    for (int i = 0; i < 8; ++i) p.h[i] = __float2half(s[i]);
    P4[o] = p.u;
  } else if (o < 49152) {
    int o3 = o - 32768;
    int t = o3 & 511, rc = o3 >> 9, c = rc >> 3, r = rc & 7;
    int j = ((r >> 1) << 8) + ((t >> 2) << 1) + (r & 1);
    int k = ((t & 3) << 5) + c * 8;
    const float* s = Wih + j * ND + k;
#pragma unroll
    for (int i = 0; i < 8; ++i) p.h[i] = __float2half(s[i]);
    PIH[o3] = p.u;
  }
}

// px kernel: R2-R4 structure; R7 changes only the row->output mapping (sel4
// argument order) to produce the gate-minor px layout px[ts][n][g].
// Store addressing is bit-identical to R4 (verified coalescing).
__global__ __launch_bounds__(512, 2)
void px_kernel(const float* __restrict__ xv, const float* __restrict__ xl,
               const float* __restrict__ xu, const uint4* __restrict__ PIH,
               __half* __restrict__ px) {
  __shared__ __align__(16) __half sv[32 * ND];
  __shared__ __align__(16) __half sm[32 * ND];
  __shared__ __align__(16) __half sr[32 * ND];
  const int t = threadIdx.x;
  const int q = t & 3;
  const int r0 = blockIdx.x * 32;
  uint4 w[4][8];
#pragma unroll
  for (int c = 0; c < 4; ++c)
#pragma unroll
    for (int r = 0; r < 8; ++r)
      w[c][r] = PIH[((c * 8 + r) << 9) + t];
  {
    const float4* v4 = (const float4*)(xv + (size_t)r0 * ND);
    const float4* l4 = (const float4*)(xl + (size_t)r0 * ND);
    const float4* u4 = (const float4*)(xu + (size_t)r0 * ND);
    __half2* sv2 = (__half2*)sv; __half2* sm2 = (__half2*)sm; __half2* sr2 = (__half2*)sr;
    for (int i = t; i < 1024; i += 512) {
      float4 v = v4[i], l = l4[i], u = u4[i];
      sv2[2*i]   = __floats2half2_rn(v.x, v.y);
      sv2[2*i+1] = __floats2half2_rn(v.z, v.w);
      sm2[2*i]   = __floats2half2_rn(0.5f*(l.x+u.x), 0.5f*(l.y+u.y));
      sm2[2*i+1] = __floats2half2_rn(0.5f*(l.z+u.z), 0.5f*(l.w+u.w));
      sr2[2*i]   = __floats2half2_rn(0.5f*(u.x-l.x), 0.5f*(u.y-l.y));
      sr2[2*i+1] = __floats2half2_rn(0.5f*(u.z-l.z), 0.5f*(u.w-l.w));
    }
  }
  __syncthreads();
  const uint4* bv = (const uint4*)sv;
  const uint4* bm = (const uint4*)sm;
  const uint4* br = (const uint4*)sr;
  for (int rr = 0; rr < 32; ++rr) {
    uint4 hv[4], hm[4], hr[4];
    const int base = rr * 16 + q * 4;
#pragma unroll
    for (int i = 0; i < 4; ++i) { hv[i] = bv[base+i]; hm[i] = bm[base+i]; hr[i] = br[base+i]; }
    float A[8][3];
#pragma unroll
    for (int r = 0; r < 8; ++r) { A[r][0] = 0.f; A[r][1] = 0.f; A[r][2] = 0.f; }
#pragma unroll
    for (int c = 0; c < 4; ++c)
#pragma unroll
      for (int r = 0; r < 8; ++r) {
        accV(w[c][r], hv[c], A[r][0]);
        accMR(w[c][r], hm[c], hr[c], A[r][1], A[r][2]);
      }
#pragma unroll
    for (int r = 0; r < 8; ++r) {
      A[r][0] = qsum4(A[r][0]); A[r][1] = qsum4(A[r][1]); A[r][2] = qsum4(A[r][2]);
    }
    // R7 gate-minor mapping: lane q emits rows {jp(.,rv0(q)), jp(.,rv1(q))}
    // rv0: q0->0 q1->4 q2->1 q3->5 ; rv1: q0->2 q1->6 q2->3 q3->7
    float v0 = sel4(A[0][0], A[4][0], A[1][0], A[5][0], q);
    float m0 = sel4(A[0][1], A[4][1], A[1][1], A[5][1], q);
    float d0 = sel4(A[0][2], A[4][2], A[1][2], A[5][2], q);
    float v1 = sel4(A[2][0], A[6][0], A[3][0], A[7][0], q);
    float m1 = sel4(A[2][1], A[6][1], A[3][1], A[7][1], q);
    float d1 = sel4(A[2][2], A[6][2], A[3][2], A[7][2], q);
    size_t ob = (size_t)(r0 + rr) * G4;
    ((__half2*)(px + ob))[t]             = __floats2half2_rn(v0, v1);
    ((__half2*)(px + CSTRIDE + ob))[t]   = __floats2half2_rn(m0 - d0, m1 - d1);
    ((__half2*)(px + 2*CSTRIDE + ob))[t] = __floats2half2_rn(m0 + d0, m1 + d1);
  }
}

// Recurrence (R7): gate-minor full-K mapping, ONE barrier per step.
// 128 blocks: blockIdx<64 -> val LSTM for batch b; >=64 -> interval LSTM.
// Thread t: unit n = t>>2, gate q = t&3; computes row j = 256q + n over full
// K=256 (no K-split, no qsum/sel). After gact, a 4/8-op DPP quad-broadcast
// gathers i,f,g,o inside the quad; cell update runs redundantly on all lanes
// (pure VALU; no sG round-trip, no divergent t<NH tail, no second barrier).
// sH (h mid/rad as halfs) double-buffered: read buf, write buf^1, one barrier.
// W tiers: c=0..23 VGPR-pinned (96 regs, asm), c=24..31 LDS (128 KiB).
// px: gate-minor layout -> load is coalesced pxb[ts*G4 + t], one-step prefetch.
__global__ __launch_bounds__(1024, 4)
void lstm_kernel(const uint4* __restrict__ P4, const __half* __restrict__ px,
                 const float* __restrict__ bias, float* __restrict__ out) {
  __shared__ uint4 sLW[8192];                     // 128 KiB: W chunks c=24..31
  __shared__ __align__(16) __half sH[2][2][256];  // [buf][comp][unit]; comp0=mid/hv, comp1=rad
  const int t = threadIdx.x;
  const bool intv = blockIdx.x >= NB;
  const int b = intv ? blockIdx.x - NB : blockIdx.x;
  const int q = t & 3;
  const int n = t >> 2;
  // pinned W chunks c=0..23 (96 VGPRs)
  uint4 Wp[24];
#pragma unroll
  for (int c = 0; c < 24; ++c)
    Wp[c] = P4[(c << 10) + t];
#pragma unroll
  for (int c = 0; c < 24; ++c)
    asm volatile("" : "+v"(Wp[c].x), "+v"(Wp[c].y), "+v"(Wp[c].z), "+v"(Wp[c].w));
  // stage c=24..31 into LDS (once; weights are step-invariant)
#pragma unroll
  for (int c = 0; c < 8; ++c)
    sLW[(c << 10) + t] = P4[((24 + c) << 10) + t];
  const float bt_ = bias[(q << 8) + n];           // bias of row j = 256q + n
  const bool is_tanh = (q == 2);                  // gate g
  if (t < 512) ((unsigned*)sH)[t] = 0u;           // zero both h buffers (2048 B)
  __syncthreads();
  const __half* pxb = px + (size_t)b * NT * G4;
  float* outb = out + (size_t)b * NT * NH;

  if (!intv) {
    // ---------------- point-value LSTM ----------------
    float cv = 0.f, hv_p = 0.f;
    int buf = 0;
    float pv = __half2float(pxb[t]);
    for (int ts = 0; ts < NT; ++ts) {
      if (ts > 0 && q == 1) outb[(size_t)(ts - 1) * NH + n] = hv_p;
      const int tsn = (ts + 1 < NT) ? ts + 1 : ts;
      float nv = __half2float(pxb[(size_t)tsn * G4 + t]);
      const uint4* sHb = (const uint4*)(&sH[buf][0][0]);
      float A = 0.f;
#pragma unroll
      for (int c = 0; c < 24; ++c) {
        uint4 hv = sHb[c];                         // wave-uniform broadcast
        accV(Wp[c], hv, A);
      }
#pragma unroll
      for (int c = 0; c < 8; ++c) {
        uint4 wl = sLW[(c << 10) + t];
        uint4 hv = sHb[24 + c];
        accV(wl, hv, A);
      }
      float g = gact(pv + bt_ + A, is_tanh);       // lane q = gate q
      float ig = qb<0x00>(g), fg = qb<0x55>(g), gg = qb<0xAA>(g), og = qb<0xFF>(g);
      cv = fmaf(fg, cv, ig * gg);
      float hvn = og * tanh_f(cv);
      hv_p = hvn;
      if (q == 0) sH[buf ^ 1][0][n] = __float2half(hvn);
      __syncthreads();
      buf ^= 1;
      pv = nv;
    }
    if (q == 1) outb[(size_t)(NT - 1) * NH + n] = hv_p;
  } else {
    // ---------------- interval (lb/ub) LSTM ----------------
    float cl = 0.f, cu = 0.f, hl_p = 0.f, hu_p = 0.f;
    int buf = 0;
    const __half* pxl = pxb + CSTRIDE;
    const __half* pxu = pxb + 2 * CSTRIDE;
    float pl = __half2float(pxl[t]);
    float pu = __half2float(pxu[t]);
    for (int ts = 0; ts < NT; ++ts) {
      if (ts > 0) {
        if (q == 2)      outb[OSTRIDE + (size_t)(ts - 1) * NH + n] = hl_p;
        else if (q == 3) outb[2 * OSTRIDE + (size_t)(ts - 1) * NH + n] = hu_p;
      }
      const int tsn = (ts + 1 < NT) ? ts + 1 : ts;
      float nl = __half2float(pxl[(size_t)tsn * G4 + t]);
      float nu = __half2float(pxu[(size_t)tsn * G4 + t]);
      const uint4* sHb = (const uint4*)(&sH[buf][0][0]);
      float M = 0.f, R = 0.f;
#pragma unroll
      for (int c = 0; c < 24; ++c) {
        uint4 hm = sHb[c];                         // wave-uniform broadcast
        uint4 hr = sHb[32 + c];
        accMR(Wp[c], hm, hr, M, R);
      }
#pragma unroll
      for (int c = 0; c < 8; ++c) {
        uint4 wl = sLW[(c << 10) + t];
        uint4 hm = sHb[24 + c];
        uint4 hr = sHb[56 + c];
        accMR(wl, hm, hr, M, R);
      }
      float gl = gact(pl + bt_ + (M - R), is_tanh);
      float gu = gact(pu + bt_ + (M + R), is_tanh);
      float il = qb<0x00>(gl), fl = qb<0x55>(gl), gl_ = qb<0xAA>(gl), ol = qb<0xFF>(gl);
      float iu = qb<0x00>(gu), fu = qb<0x55>(gu), gu_ = qb<0xAA>(gu), ou = qb<0xFF>(gu);
      float p0 = fl * cl, p1 = fl * cu, p2 = fu * cl, p3 = fu * cu;
      float fcl = fminf(fminf(p0, p1), fminf(p2, p3));
      float fcu = fmaxf(fmaxf(p0, p1), fmaxf(p2, p3));
      p0 = il * gl_; p1 = il * gu_; p2 = iu * gl_; p3 = iu * gu_;
      float igl = fminf(fminf(p0, p1), fminf(p2, p3));
      float igu = fmaxf(fmaxf(p0, p1), fmaxf(p2, p3));
      cl = fcl + igl; cu = fcu + igu;
      float tl = tanh_f(cl), tu = tanh_f(cu);
      p0 = ol * tl; p1 = ol * tu; p2 = ou * tl; p3 = ou * tu;
      float hl = fminf(fminf(p0, p1), fminf(p2, p3));
      float hu = fmaxf(fmaxf(p0, p1), fmaxf(p2, p3));
      hl_p = hl; hu_p = hu;
      if (q == 0)      sH[buf ^ 1][0][n] = __float2half(0.5f * (hl + hu));
      else if (q == 1) sH[buf ^ 1][1][n] = __float2half(0.5f * (hu - hl));
      __syncthreads();
      buf ^= 1;
      pl = nl; pu = nu;
    }
    if (q == 2)      outb[OSTRIDE + (size_t)(NT - 1) * NH + n] = hl_p;
    else if (q == 3) outb[2 * OSTRIDE + (size_t)(NT - 1) * NH + n] = hu_p;
  }
}

extern "C" void kernel_launch(void* const* d_in, const int* in_sizes, int n_in,
                              void* d_out, int out_size, void* d_ws, size_t ws_size,
                              hipStream_t stream) {
  const float* xv   = (const float*)d_in[0];
  const float* xl   = (const float*)d_in[1];
  const float* xu   = (const float*)d_in[2];
  const float* Wih  = (const float*)d_in[3];
  const float* Whh  = (const float*)d_in[4];
  const float* bias = (const float*)d_in[5];
  float* out = (float*)d_out;
  char* ws = (char*)d_ws;
  uint4*  P4  = (uint4*)ws;                    // 512 KiB (recurrent W, gate-minor full-K layout)
  uint4*  PIH = (uint4*)(ws + 512 * 1024);     // 256 KiB (px weights)
  __half* px  = (__half*)(ws + 768 * 1024);    // 192 MiB

  conv_w_kernel<<<192, 256, 0, stream>>>(Whh, Wih, P4, PIH);
  px_kernel<<<NBT / 32, 512, 0, stream>>>(xv, xl, xu, PIH, px);
  lstm_kernel<<<2 * NB, 1024, 0, stream>>>(P4, px, bias, out);
}

// Round 4
// 2479.881 us; speedup vs baseline: 1.1093x; 1.1093x over previous
//
#include <hip/hip_runtime.h>
#include <hip/hip_fp16.h>

#define NB 64
#define NT 512
#define ND 128
#define NH 256
#define G4 1024                     // 4*H
#define NBT (NB*NT)                 // 32768
#define CSTRIDE ((size_t)NBT * G4)  // elements per interval component of px
#define OSTRIDE ((size_t)NBT * NH)  // elements per interval component of out

typedef _Float16 f16x2 __attribute__((ext_vector_type(2)));

__device__ __forceinline__ float fdot2u(unsigned a, unsigned b, float c) {
  return __builtin_amdgcn_fdot2(__builtin_bit_cast(f16x2, a),
                                __builtin_bit_cast(f16x2, b), c, false);
}

// val-only: 4 fdot2
__device__ __forceinline__ void accV(uint4 w, uint4 hv, float& av) {
  av = fdot2u(w.x, hv.x, av);
  av = fdot2u(w.y, hv.y, av);
  av = fdot2u(w.z, hv.z, av);
  av = fdot2u(w.w, hv.w, av);
}
// interval: mid += w.hm, rad += |w|.hr
__device__ __forceinline__ void accMR(uint4 w, uint4 hm, uint4 hr, float& am, float& ar) {
  const unsigned M = 0x7FFF7FFFu;
  am = fdot2u(w.x, hm.x, am); ar = fdot2u(w.x & M, hr.x, ar);
  am = fdot2u(w.y, hm.y, am); ar = fdot2u(w.y & M, hr.y, ar);
  am = fdot2u(w.z, hm.z, am); ar = fdot2u(w.z & M, hr.z, ar);
  am = fdot2u(w.w, hm.w, am); ar = fdot2u(w.w & M, hr.w, ar);
}

// quad all-reduce via DPP quad_perm (verified R2-R4)
__device__ __forceinline__ float qsum4(float x) {
  int v = __builtin_amdgcn_update_dpp(0, __builtin_bit_cast(int, x), 0xB1, 0xF, 0xF, true);
  x += __builtin_bit_cast(float, v);
  v = __builtin_amdgcn_update_dpp(0, __builtin_bit_cast(int, x), 0x4E, 0xF, 0xF, true);
  x += __builtin_bit_cast(float, v);
  return x;
}
__device__ __forceinline__ float sel4(float x0, float x1, float x2, float x3, int q) {
  float a = (q & 1) ? x1 : x0;
  float b = (q & 1) ? x3 : x2;
  return (q & 2) ? b : a;
}

__device__ __forceinline__ float rcpf(float x) { return __builtin_amdgcn_rcpf(x); }
__device__ __forceinline__ float gact(float x, bool is_tanh) {
  float s = is_tanh ? -2.0f : -1.0f;
  float e = __expf(s * x);
  float r = rcpf(1.0f + e);
  return is_tanh ? fmaf(2.0f, r, -1.0f) : r;
}
__device__ __forceinline__ float tanh_f(float x) {
  return fmaf(2.0f, rcpf(1.0f + __expf(-2.0f * x)), -1.0f);
}

// R8: LDS-only barrier. __syncthreads() compiles to s_waitcnt vmcnt(0)
// expcnt(0) lgkmcnt(0) + s_barrier, which drains pending GLOBAL ops (out
// stores, px prefetch loads) onto the per-step critical path. The in-loop
// hazards are LDS-only (sG, sH), so lgkmcnt(0)+s_barrier suffices (m201
// pattern). Global stores/loads float across the barrier and complete in
// the shadow of the next dot.
__device__ __forceinline__ void bar_lds() {
  asm volatile("s_waitcnt lgkmcnt(0)\n\ts_barrier" ::: "memory");
}

// Pack weights f32->f16.  (R4 layout, verified)
// P4[(r*8+c8)*1024 + t] = Whh[j=(t>>2)*4 + r][k=(t&3)*64 + c8*8 ..+8], r=0..3
//   (R6 tiering: r=0,1,2 VGPR-pinned; r=3 LDS)
// PIH[(c*8+r)*512 + t]  = Wih[(t>>2)*8 + r][(t&3)*32 + c*8 ..+8]  (px kernel, verified R2-R4)
__global__ void conv_w_kernel(const float* __restrict__ Whh, const float* __restrict__ Wih,
                              uint4* __restrict__ P4, uint4* __restrict__ PIH) {
  int o = blockIdx.x * 256 + threadIdx.x;
  union { uint4 u; __half h[8]; } p;
  if (o < 32768) {
    int t = o & 1023, rc = o >> 10, r = rc >> 3, c8 = rc & 7;
    int j = ((t >> 2) << 2) + r, k = ((t & 3) << 6) + c8 * 8;
    const float* s = Whh + j * NH + k;
#pragma unroll
    for (int i = 0; i < 8; ++i) p.h[i] = __float2half(s[i]);
    P4[o] = p.u;
  } else if (o < 49152) {
    int o3 = o - 32768;
    int t = o3 & 511, rc = o3 >> 9, c = rc >> 3, r = rc & 7;
    int j = ((t >> 2) << 3) + r, k = ((t & 3) << 5) + c * 8;
    const float* s = Wih + j * ND + k;
#pragma unroll
    for (int i = 0; i < 8; ++i) p.h[i] = __float2half(s[i]);
    PIH[o3] = p.u;
  }
}

// px kernel: unchanged from R2-R4 (verified).
__global__ __launch_bounds__(512, 2)
void px_kernel(const float* __restrict__ xv, const float* __restrict__ xl,
               const float* __restrict__ xu, const uint4* __restrict__ PIH,
               __half* __restrict__ px) {
  __shared__ __align__(16) __half sv[32 * ND];
  __shared__ __align__(16) __half sm[32 * ND];
  __shared__ __align__(16) __half sr[32 * ND];
  const int t = threadIdx.x;
  const int q = t & 3;
  const int r0 = blockIdx.x * 32;
  uint4 w[4][8];
#pragma unroll
  for (int c = 0; c < 4; ++c)
#pragma unroll
    for (int r = 0; r < 8; ++r)
      w[c][r] = PIH[((c * 8 + r) << 9) + t];
  {
    const float4* v4 = (const float4*)(xv + (size_t)r0 * ND);
    const float4* l4 = (const float4*)(xl + (size_t)r0 * ND);
    const float4* u4 = (const float4*)(xu + (size_t)r0 * ND);
    __half2* sv2 = (__half2*)sv; __half2* sm2 = (__half2*)sm; __half2* sr2 = (__half2*)sr;
    for (int i = t; i < 1024; i += 512) {
      float4 v = v4[i], l = l4[i], u = u4[i];
      sv2[2*i]   = __floats2half2_rn(v.x, v.y);
      sv2[2*i+1] = __floats2half2_rn(v.z, v.w);
      sm2[2*i]   = __floats2half2_rn(0.5f*(l.x+u.x), 0.5f*(l.y+u.y));
      sm2[2*i+1] = __floats2half2_rn(0.5f*(l.z+u.z), 0.5f*(l.w+u.w));
      sr2[2*i]   = __floats2half2_rn(0.5f*(u.x-l.x), 0.5f*(u.y-l.y));
      sr2[2*i+1] = __floats2half2_rn(0.5f*(u.z-l.z), 0.5f*(u.w-l.w));
    }
  }
  __syncthreads();
  const uint4* bv = (const uint4*)sv;
  const uint4* bm = (const uint4*)sm;
  const uint4* br = (const uint4*)sr;
  for (int rr = 0; rr < 32; ++rr) {
    uint4 hv[4], hm[4], hr[4];
    const int base = rr * 16 + q * 4;
#pragma unroll
    for (int i = 0; i < 4; ++i) { hv[i] = bv[base+i]; hm[i] = bm[base+i]; hr[i] = br[base+i]; }
    float A[8][3];
#pragma unroll
    for (int r = 0; r < 8; ++r) { A[r][0] = 0.f; A[r][1] = 0.f; A[r][2] = 0.f; }
#pragma unroll
    for (int c = 0; c < 4; ++c)
#pragma unroll
      for (int r = 0; r < 8; ++r) {
        accV(w[c][r], hv[c], A[r][0]);
        accMR(w[c][r], hm[c], hr[c], A[r][1], A[r][2]);
      }
#pragma unroll
    for (int r = 0; r < 8; ++r) {
      A[r][0] = qsum4(A[r][0]); A[r][1] = qsum4(A[r][1]); A[r][2] = qsum4(A[r][2]);
    }
    float v0 = sel4(A[0][0], A[2][0], A[4][0], A[6][0], q);
    float m0 = sel4(A[0][1], A[2][1], A[4][1], A[6][1], q);
    float d0 = sel4(A[0][2], A[2][2], A[4][2], A[6][2], q);
    float v1 = sel4(A[1][0], A[3][0], A[5][0], A[7][0], q);
    float m1 = sel4(A[1][1], A[3][1], A[5][1], A[7][1], q);
    float d1 = sel4(A[1][2], A[3][2], A[5][2], A[7][2], q);
    size_t ob = (size_t)(r0 + rr) * G4;
    ((__half2*)(px + ob))[t]             = __floats2half2_rn(v0, v1);
    ((__half2*)(px + CSTRIDE + ob))[t]   = __floats2half2_rn(m0 - d0, m1 - d1);
    ((__half2*)(px + 2*CSTRIDE + ob))[t] = __floats2half2_rn(m0 + d0, m1 + d1);
  }
}

// Recurrence (R6 structure, verified; R8 = raw LDS-only barriers ONLY):
// 128 blocks: blockIdx<64 -> val LSTM for batch row b; >=64 -> interval LSTM.
// 1024 threads: q=t&3 K-quarter, 4 rows/thread (j = (t>>2)*4+r); after quad
// reduce+sel4 thread t owns gate row t exactly (px/bias/sG accesses = [t]).
// W tiers: r=0,1,2 VGPR-pinned (96 regs, asm), r=3 in LDS (128 KiB, loaded
// once). ZERO per-step global weight traffic. px prefetched one step ahead;
// out stores deferred one step; both float across the raw barriers.
__global__ __launch_bounds__(1024, 4)
void lstm_kernel(const uint4* __restrict__ P4, const __half* __restrict__ px,
                 const float* __restrict__ bias, float* __restrict__ out) {
  __shared__ uint4 sLW[8192];                     // 128 KiB: W row-index r=3
  __shared__ __align__(16) __half sH[2][4][72];   // [slot][q][64+8 pad]; val: slot0=hv; intv: 0=hm,1=hr
  __shared__ __align__(16) float sG[2][G4];       // val: slot0; intv: 0=g_lb, 1=g_ub
  const int t = threadIdx.x;
  const bool intv = blockIdx.x >= NB;
  const int b = intv ? blockIdx.x - NB : blockIdx.x;
  const int q = t & 3;
  // pinned W rows r=0,1,2 (96 VGPRs)
  uint4 Wp[3][8];
#pragma unroll
  for (int r = 0; r < 3; ++r)
#pragma unroll
    for (int c8 = 0; c8 < 8; ++c8)
      Wp[r][c8] = P4[((r * 8 + c8) << 10) + t];
#pragma unroll
  for (int r = 0; r < 3; ++r)
#pragma unroll
    for (int c8 = 0; c8 < 8; ++c8)
      asm volatile("" : "+v"(Wp[r][c8].x), "+v"(Wp[r][c8].y),
                        "+v"(Wp[r][c8].z), "+v"(Wp[r][c8].w));
  // stage r=3 into LDS (once; weights are step-invariant)
#pragma unroll
  for (int c8 = 0; c8 < 8; ++c8)
    sLW[(c8 << 10) + t] = P4[((24 + c8) << 10) + t];
  const float bt_ = bias[t];
  const bool is_tanh = ((t >> 8) == 2);           // rows 512..767 = gate g
  if (t < 288) ((unsigned*)sH)[t] = 0u;           // zero h (1152 B)
  __syncthreads();
  const __half* pxb = px + (size_t)b * NT * G4;
  float* outb = out + (size_t)b * NT * NH;

  if (!intv) {
    // ---------------- point-value LSTM ----------------
    float cv = 0.f, hv_p = 0.f;
    float pv = __half2float(pxb[t]);
    for (int ts = 0; ts < NT; ++ts) {
      if (ts > 0 && t < NH) outb[(size_t)(ts - 1) * NH + t] = hv_p;
      const int tsn = (ts + 1 < NT) ? ts + 1 : ts;
      float nv = __half2float(pxb[(size_t)tsn * G4 + t]);
      float A0 = 0.f, A1 = 0.f, A2 = 0.f, A3 = 0.f;
#pragma unroll
      for (int c8 = 0; c8 < 8; ++c8) {
        uint4 wl3 = sLW[(c8 << 10) + t];                // LDS r=3
        uint4 hv = *(const uint4*)(&sH[0][q][c8 * 8]);  // quad-distinct broadcast
        accV(Wp[0][c8], hv, A0);
        accV(Wp[1][c8], hv, A1);
        accV(Wp[2][c8], hv, A2);
        accV(wl3, hv, A3);
      }
      A0 = qsum4(A0); A1 = qsum4(A1); A2 = qsum4(A2); A3 = qsum4(A3);
      float av = sel4(A0, A1, A2, A3, q);               // row t
      float gt = gact(pv + bt_ + av, is_tanh);
      sG[0][t] = gt;
      bar_lds();
      if (t < NH) {
        float iv = sG[0][t], fv = sG[0][NH + t], gv = sG[0][2 * NH + t], ov = sG[0][3 * NH + t];
        cv = fmaf(fv, cv, iv * gv);
        float hvn = ov * tanh_f(cv);
        hv_p = hvn;
        sH[0][t >> 6][t & 63] = __float2half(hvn);
      }
      bar_lds();
      pv = nv;
    }
    if (t < NH) outb[(size_t)(NT - 1) * NH + t] = hv_p;
  } else {
    // ---------------- interval (lb/ub) LSTM ----------------
    float cl = 0.f, cu = 0.f, hl_p = 0.f, hu_p = 0.f;
    float pl = __half2float(pxb[CSTRIDE + t]);
    float pu = __half2float(pxb[2 * CSTRIDE + t]);
    for (int ts = 0; ts < NT; ++ts) {
      if (ts > 0 && t < NH) {
        size_t o = (size_t)(ts - 1) * NH + t;
        outb[OSTRIDE + o] = hl_p; outb[2 * OSTRIDE + o] = hu_p;
      }
      const int tsn = (ts + 1 < NT) ? ts + 1 : ts;
      float nl = __half2float(pxb[(size_t)tsn * G4 + CSTRIDE + t]);
      float nu = __half2float(pxb[(size_t)tsn * G4 + 2 * CSTRIDE + t]);
      float M0 = 0.f, M1 = 0.f, M2 = 0.f, M3 = 0.f;
      float R0 = 0.f, R1 = 0.f, R2 = 0.f, R3 = 0.f;
#pragma unroll
      for (int c8 = 0; c8 < 8; ++c8) {
        uint4 wl3 = sLW[(c8 << 10) + t];                // LDS r=3
        uint4 hm = *(const uint4*)(&sH[0][q][c8 * 8]);
        uint4 hr = *(const uint4*)(&sH[1][q][c8 * 8]);
        accMR(Wp[0][c8], hm, hr, M0, R0);
        accMR(Wp[1][c8], hm, hr, M1, R1);
        accMR(Wp[2][c8], hm, hr, M2, R2);
        accMR(wl3, hm, hr, M3, R3);
      }
      M0 = qsum4(M0); M1 = qsum4(M1); M2 = qsum4(M2); M3 = qsum4(M3);
      R0 = qsum4(R0); R1 = qsum4(R1); R2 = qsum4(R2); R3 = qsum4(R3);
      float m = sel4(M0, M1, M2, M3, q);                // row t
      float d = sel4(R0, R1, R2, R3, q);
      float gl = gact(pl + bt_ + (m - d), is_tanh);
      float gu = gact(pu + bt_ + (m + d), is_tanh);
      sG[0][t] = gl; sG[1][t] = gu;
      bar_lds();
      if (t < NH) {
        float il = sG[0][t],        iu = sG[1][t];
        float fl = sG[0][NH+t],     fu = sG[1][NH+t];
        float gl_ = sG[0][2*NH+t],  gu_ = sG[1][2*NH+t];
        float ol = sG[0][3*NH+t],   ou = sG[1][3*NH+t];
        float p0 = fl*cl, p1 = fl*cu, p2 = fu*cl, p3 = fu*cu;
        float fcl = fminf(fminf(p0,p1), fminf(p2,p3));
        float fcu = fmaxf(fmaxf(p0,p1), fmaxf(p2,p3));
        p0 = il*gl_; p1 = il*gu_; p2 = iu*gl_; p3 = iu*gu_;
        float igl = fminf(fminf(p0,p1), fminf(p2,p3));
        float igu = fmaxf(fmaxf(p0,p1), fmaxf(p2,p3));
        cl = fcl + igl; cu = fcu + igu;
        float tl = tanh_f(cl), tu = tanh_f(cu);
        p0 = ol*tl; p1 = ol*tu; p2 = ou*tl; p3 = ou*tu;
        float hl = fminf(fminf(p0,p1), fminf(p2,p3));
        float hu = fmaxf(fmaxf(p0,p1), fmaxf(p2,p3));
        hl_p = hl; hu_p = hu;
        sH[0][t >> 6][t & 63] = __float2half(0.5f * (hl + hu));
        sH[1][t >> 6][t & 63] = __float2half(0.5f * (hu - hl));
      }
      bar_lds();
      pl = nl; pu = nu;
    }
    if (t < NH) {
      size_t o = (size_t)(NT - 1) * NH + t;
      outb[OSTRIDE + o] = hl_p; outb[2 * OSTRIDE + o] = hu_p;
    }
  }
}

extern "C" void kernel_launch(void* const* d_in, const int* in_sizes, int n_in,
                              void* d_out, int out_size, void* d_ws, size_t ws_size,
                              hipStream_t stream) {
  const float* xv   = (const float*)d_in[0];
  const float* xl   = (const float*)d_in[1];
  const float* xu   = (const float*)d_in[2];
  const float* Wih  = (const float*)d_in[3];
  const float* Whh  = (const float*)d_in[4];
  const float* bias = (const float*)d_in[5];
  float* out = (float*)d_out;
  char* ws = (char*)d_ws;
  uint4*  P4  = (uint4*)ws;                    // 512 KiB (recurrent W, 4-row layout)
  uint4*  PIH = (uint4*)(ws + 512 * 1024);     // 256 KiB (px weights)
  __half* px  = (__half*)(ws + 768 * 1024);    // 192 MiB

  conv_w_kernel<<<192, 256, 0, stream>>>(Whh, Wih, P4, PIH);
  px_kernel<<<NBT / 32, 512, 0, stream>>>(xv, xl, xu, PIH, px);
  lstm_kernel<<<2 * NB, 1024, 0, stream>>>(P4, px, bias, out);
}

// Round 5
// 2277.894 us; speedup vs baseline: 1.2077x; 1.0887x over previous
//
#include <hip/hip_runtime.h>
#include <hip/hip_fp16.h>

#define NB 64
#define NT 512
#define ND 128
#define NH 256
#define G4 1024                     // 4*H
#define NBT (NB*NT)                 // 32768
#define CSTRIDE ((size_t)NBT * G4)  // elements per interval component of px
#define OSTRIDE ((size_t)NBT * NH)  // elements per interval component of out

typedef _Float16 f16x2 __attribute__((ext_vector_type(2)));

__device__ __forceinline__ float fdot2u(unsigned a, unsigned b, float c) {
  return __builtin_amdgcn_fdot2(__builtin_bit_cast(f16x2, a),
                                __builtin_bit_cast(f16x2, b), c, false);
}

// val-only: 4 fdot2
__device__ __forceinline__ void accV(uint4 w, uint4 hv, float& av) {
  av = fdot2u(w.x, hv.x, av);
  av = fdot2u(w.y, hv.y, av);
  av = fdot2u(w.z, hv.z, av);
  av = fdot2u(w.w, hv.w, av);
}
// interval: mid += w.hm, rad += |w|.hr
__device__ __forceinline__ void accMR(uint4 w, uint4 hm, uint4 hr, float& am, float& ar) {
  const unsigned M = 0x7FFF7FFFu;
  am = fdot2u(w.x, hm.x, am); ar = fdot2u(w.x & M, hr.x, ar);
  am = fdot2u(w.y, hm.y, am); ar = fdot2u(w.y & M, hr.y, ar);
  am = fdot2u(w.z, hm.z, am); ar = fdot2u(w.z & M, hr.z, ar);
  am = fdot2u(w.w, hm.w, am); ar = fdot2u(w.w & M, hr.w, ar);
}

// quad all-reduce via DPP quad_perm (verified R2-R4)
__device__ __forceinline__ float qsum4(float x) {
  int v = __builtin_amdgcn_update_dpp(0, __builtin_bit_cast(int, x), 0xB1, 0xF, 0xF, true);
  x += __builtin_bit_cast(float, v);
  v = __builtin_amdgcn_update_dpp(0, __builtin_bit_cast(int, x), 0x4E, 0xF, 0xF, true);
  x += __builtin_bit_cast(float, v);
  return x;
}
__device__ __forceinline__ float sel4(float x0, float x1, float x2, float x3, int q) {
  float a = (q & 1) ? x1 : x0;
  float b = (q & 1) ? x3 : x2;
  return (q & 2) ? b : a;
}

__device__ __forceinline__ float rcpf(float x) { return __builtin_amdgcn_rcpf(x); }
__device__ __forceinline__ float gact(float x, bool is_tanh) {
  float s = is_tanh ? -2.0f : -1.0f;
  float e = __expf(s * x);
  float r = rcpf(1.0f + e);
  return is_tanh ? fmaf(2.0f, r, -1.0f) : r;
}
__device__ __forceinline__ float tanh_f(float x) {
  return fmaf(2.0f, rcpf(1.0f + __expf(-2.0f * x)), -1.0f);
}
// chain-shaped 4-way min/max -> v_min3/v_max3 fusion (2 ops instead of 3)
__device__ __forceinline__ float min4c(float a, float b, float c, float d) {
  return fminf(fminf(fminf(a, b), c), d);
}
__device__ __forceinline__ float max4c(float a, float b, float c, float d) {
  return fmaxf(fmaxf(fmaxf(a, b), c), d);
}

// Pack weights f32->f16.  (R4 layout, verified)
// P4[(r*8+c8)*1024 + t] = Whh[j=(t>>2)*4 + r][k=(t&3)*64 + c8*8 ..+8], r=0..3
//   (R6 tiering: r=0,1,2 VGPR-pinned; r=3 LDS)
// PIH[(c*8+r)*512 + t]  = Wih[(t>>2)*8 + r][(t&3)*32 + c*8 ..+8]  (px kernel, verified R2-R4)
__global__ void conv_w_kernel(const float* __restrict__ Whh, const float* __restrict__ Wih,
                              uint4* __restrict__ P4, uint4* __restrict__ PIH) {
  int o = blockIdx.x * 256 + threadIdx.x;
  union { uint4 u; __half h[8]; } p;
  if (o < 32768) {
    int t = o & 1023, rc = o >> 10, r = rc >> 3, c8 = rc & 7;
    int j = ((t >> 2) << 2) + r, k = ((t & 3) << 6) + c8 * 8;
    const float* s = Whh + j * NH + k;
#pragma unroll
    for (int i = 0; i < 8; ++i) p.h[i] = __float2half(s[i]);
    P4[o] = p.u;
  } else if (o < 49152) {
    int o3 = o - 32768;
    int t = o3 & 511, rc = o3 >> 9, c = rc >> 3, r = rc & 7;
    int j = ((t >> 2) << 3) + r, k = ((t & 3) << 5) + c * 8;
    const float* s = Wih + j * ND + k;
#pragma unroll
    for (int i = 0; i < 8; ++i) p.h[i] = __float2half(s[i]);
    PIH[o3] = p.u;
  }
}

// px kernel: R2-R4 verified structure. R9: bias folded in (b0/b1 per emitted
// row), intv components stored INTERLEAVED as half2(lb,ub) per row at CSTRIDE.
// Lane t emits G4-rows 2t and 2t+1 (j0=2t, j1=2t+1; verified mapping).
__global__ __launch_bounds__(512, 2)
void px_kernel(const float* __restrict__ xv, const float* __restrict__ xl,
               const float* __restrict__ xu, const uint4* __restrict__ PIH,
               const float* __restrict__ bias, __half* __restrict__ px) {
  __shared__ __align__(16) __half sv[32 * ND];
  __shared__ __align__(16) __half sm[32 * ND];
  __shared__ __align__(16) __half sr[32 * ND];
  const int t = threadIdx.x;
  const int q = t & 3;
  const int r0 = blockIdx.x * 32;
  const float b0 = bias[2 * t];
  const float b1 = bias[2 * t + 1];
  uint4 w[4][8];
#pragma unroll
  for (int c = 0; c < 4; ++c)
#pragma unroll
    for (int r = 0; r < 8; ++r)
      w[c][r] = PIH[((c * 8 + r) << 9) + t];
  {
    const float4* v4 = (const float4*)(xv + (size_t)r0 * ND);
    const float4* l4 = (const float4*)(xl + (size_t)r0 * ND);
    const float4* u4 = (const float4*)(xu + (size_t)r0 * ND);
    __half2* sv2 = (__half2*)sv; __half2* sm2 = (__half2*)sm; __half2* sr2 = (__half2*)sr;
    for (int i = t; i < 1024; i += 512) {
      float4 v = v4[i], l = l4[i], u = u4[i];
      sv2[2*i]   = __floats2half2_rn(v.x, v.y);
      sv2[2*i+1] = __floats2half2_rn(v.z, v.w);
      sm2[2*i]   = __floats2half2_rn(0.5f*(l.x+u.x), 0.5f*(l.y+u.y));
      sm2[2*i+1] = __floats2half2_rn(0.5f*(l.z+u.z), 0.5f*(l.w+u.w));
      sr2[2*i]   = __floats2half2_rn(0.5f*(u.x-l.x), 0.5f*(u.y-l.y));
      sr2[2*i+1] = __floats2half2_rn(0.5f*(u.z-l.z), 0.5f*(u.w-l.w));
    }
  }
  __syncthreads();
  const uint4* bv = (const uint4*)sv;
  const uint4* bm = (const uint4*)sm;
  const uint4* br = (const uint4*)sr;
  __half2* pxV = (__half2*)px;                    // val comp, half2 per 2 rows
  __half2* pxI = (__half2*)(px + CSTRIDE);        // intv comp, half2(lb,ub) per row
  for (int rr = 0; rr < 32; ++rr) {
    uint4 hv[4], hm[4], hr[4];
    const int base = rr * 16 + q * 4;
#pragma unroll
    for (int i = 0; i < 4; ++i) { hv[i] = bv[base+i]; hm[i] = bm[base+i]; hr[i] = br[base+i]; }
    float A[8][3];
#pragma unroll
    for (int r = 0; r < 8; ++r) { A[r][0] = 0.f; A[r][1] = 0.f; A[r][2] = 0.f; }
#pragma unroll
    for (int c = 0; c < 4; ++c)
#pragma unroll
      for (int r = 0; r < 8; ++r) {
        accV(w[c][r], hv[c], A[r][0]);
        accMR(w[c][r], hm[c], hr[c], A[r][1], A[r][2]);
      }
#pragma unroll
    for (int r = 0; r < 8; ++r) {
      A[r][0] = qsum4(A[r][0]); A[r][1] = qsum4(A[r][1]); A[r][2] = qsum4(A[r][2]);
    }
    float v0 = sel4(A[0][0], A[2][0], A[4][0], A[6][0], q) + b0;
    float m0 = sel4(A[0][1], A[2][1], A[4][1], A[6][1], q) + b0;
    float d0 = sel4(A[0][2], A[2][2], A[4][2], A[6][2], q);
    float v1 = sel4(A[1][0], A[3][0], A[5][0], A[7][0], q) + b1;
    float m1 = sel4(A[1][1], A[3][1], A[5][1], A[7][1], q) + b1;
    float d1 = sel4(A[1][2], A[3][2], A[5][2], A[7][2], q);
    size_t ob = (size_t)(r0 + rr) * G4;
    pxV[(ob >> 1) + t] = __floats2half2_rn(v0, v1);
    union { uint2 u; __half2 h[2]; } pi;
    pi.h[0] = __floats2half2_rn(m0 - d0, m0 + d0);  // row 2t: (lb, ub)
    pi.h[1] = __floats2half2_rn(m1 - d1, m1 + d1);  // row 2t+1
    *(uint2*)(pxI + ob + 2 * t) = pi.u;
  }
}

// Recurrence (R6 structure, verified; R9 = instruction diet only):
// 128 blocks: blockIdx<64 -> val LSTM for batch row b; >=64 -> interval LSTM.
// 1024 threads: q=t&3 K-quarter, 4 rows/thread (j = (t>>2)*4+r); after quad
// reduce+sel4 thread t owns gate row t exactly.
// W tiers: r=0,1,2 VGPR-pinned (96 regs, asm), r=3 in LDS (128 KiB, loaded
// once). ZERO per-step global weight traffic. px prefetched one step ahead
// (bias pre-folded; intv = one half2(lb,ub) load); out stores deferred one
// step. sG intv = float2(gl,gu): b64 write + 4 b64 reads.
__global__ __launch_bounds__(1024, 4)
void lstm_kernel(const uint4* __restrict__ P4, const __half* __restrict__ px,
                 float* __restrict__ out) {
  __shared__ uint4 sLW[8192];                     // 128 KiB: W row-index r=3
  __shared__ __align__(16) __half sH[2][4][72];   // [slot][q][64+8 pad]; val: slot0=hv; intv: 0=hm,1=hr
  __shared__ __align__(16) float sG[2][G4];       // val: sG[0][row]; intv: aliased as float2[row]=(gl,gu)
  float2* sGp = (float2*)sG;
  const int t = threadIdx.x;
  const bool intv = blockIdx.x >= NB;
  const int b = intv ? blockIdx.x - NB : blockIdx.x;
  const int q = t & 3;
  // pinned W rows r=0,1,2 (96 VGPRs)
  uint4 Wp[3][8];
#pragma unroll
  for (int r = 0; r < 3; ++r)
#pragma unroll
    for (int c8 = 0; c8 < 8; ++c8)
      Wp[r][c8] = P4[((r * 8 + c8) << 10) + t];
#pragma unroll
  for (int r = 0; r < 3; ++r)
#pragma unroll
    for (int c8 = 0; c8 < 8; ++c8)
      asm volatile("" : "+v"(Wp[r][c8].x), "+v"(Wp[r][c8].y),
                        "+v"(Wp[r][c8].z), "+v"(Wp[r][c8].w));
  // stage r=3 into LDS (once; weights are step-invariant)
#pragma unroll
  for (int c8 = 0; c8 < 8; ++c8)
    sLW[(c8 << 10) + t] = P4[((24 + c8) << 10) + t];
  const bool is_tanh = ((t >> 8) == 2);           // rows 512..767 = gate g
  if (t < 288) ((unsigned*)sH)[t] = 0u;           // zero h (1152 B)
  __syncthreads();
  float* outb = out + (size_t)b * NT * NH;

  if (!intv) {
    // ---------------- point-value LSTM ----------------
    const __half* pxb = px + (size_t)b * NT * G4;
    float cv = 0.f, hv_p = 0.f;
    float pv = __half2float(pxb[t]);
    for (int ts = 0; ts < NT; ++ts) {
      if (ts > 0 && t < NH) outb[(size_t)(ts - 1) * NH + t] = hv_p;
      const int tsn = (ts + 1 < NT) ? ts + 1 : ts;
      float nv = __half2float(pxb[(size_t)tsn * G4 + t]);
      float A0 = 0.f, A1 = 0.f, A2 = 0.f, A3 = 0.f;
#pragma unroll
      for (int c8 = 0; c8 < 8; ++c8) {
        uint4 wl3 = sLW[(c8 << 10) + t];                // LDS r=3
        uint4 hv = *(const uint4*)(&sH[0][q][c8 * 8]);  // quad-distinct broadcast
        accV(Wp[0][c8], hv, A0);
        accV(Wp[1][c8], hv, A1);
        accV(Wp[2][c8], hv, A2);
        accV(wl3, hv, A3);
      }
      A0 = qsum4(A0); A1 = qsum4(A1); A2 = qsum4(A2); A3 = qsum4(A3);
      float av = sel4(A0, A1, A2, A3, q);               // row t
      float gt = gact(pv + av, is_tanh);                // bias pre-folded in px
      sG[0][t] = gt;
      __syncthreads();
      if (t < NH) {
        float iv = sG[0][t], fv = sG[0][NH + t], gv = sG[0][2 * NH + t], ov = sG[0][3 * NH + t];
        cv = fmaf(fv, cv, iv * gv);
        float hvn = ov * tanh_f(cv);
        hv_p = hvn;
        sH[0][t >> 6][t & 63] = __float2half(hvn);
      }
      __syncthreads();
      pv = nv;
    }
    if (t < NH) outb[(size_t)(NT - 1) * NH + t] = hv_p;
  } else {
    // ---------------- interval (lb/ub) LSTM ----------------
    const __half2* pI = (const __half2*)(px + CSTRIDE) + (size_t)b * NT * G4;
    float cl = 0.f, cu = 0.f, hl_p = 0.f, hu_p = 0.f;
    __half2 plu = pI[t];
    for (int ts = 0; ts < NT; ++ts) {
      if (ts > 0 && t < NH) {
        size_t o = (size_t)(ts - 1) * NH + t;
        outb[OSTRIDE + o] = hl_p; outb[2 * OSTRIDE + o] = hu_p;
      }
      const int tsn = (ts + 1 < NT) ? ts + 1 : ts;
      __half2 nlu = pI[(size_t)tsn * G4 + t];
      float M0 = 0.f, M1 = 0.f, M2 = 0.f, M3 = 0.f;
      float R0 = 0.f, R1 = 0.f, R2 = 0.f, R3 = 0.f;
#pragma unroll
      for (int c8 = 0; c8 < 8; ++c8) {
        uint4 wl3 = sLW[(c8 << 10) + t];                // LDS r=3
        uint4 hm = *(const uint4*)(&sH[0][q][c8 * 8]);
        uint4 hr = *(const uint4*)(&sH[1][q][c8 * 8]);
        accMR(Wp[0][c8], hm, hr, M0, R0);
        accMR(Wp[1][c8], hm, hr, M1, R1);
        accMR(Wp[2][c8], hm, hr, M2, R2);
        accMR(wl3, hm, hr, M3, R3);
      }
      M0 = qsum4(M0); M1 = qsum4(M1); M2 = qsum4(M2); M3 = qsum4(M3);
      R0 = qsum4(R0); R1 = qsum4(R1); R2 = qsum4(R2); R3 = qsum4(R3);
      float m = sel4(M0, M1, M2, M3, q);                // row t
      float d = sel4(R0, R1, R2, R3, q);
      float pl = __low2float(plu), pu = __high2float(plu);  // bias pre-folded
      float gl = gact(pl + (m - d), is_tanh);
      float gu = gact(pu + (m + d), is_tanh);
      sGp[t] = make_float2(gl, gu);                     // one b64 write
      __syncthreads();
      if (t < NH) {
        float2 gi = sGp[t], gf = sGp[NH + t], gg = sGp[2 * NH + t], go = sGp[3 * NH + t];
        float il = gi.x, iu = gi.y, fl = gf.x, fu = gf.y;
        float gl_ = gg.x, gu_ = gg.y, ol = go.x, ou = go.y;
        float p0 = fl*cl, p1 = fl*cu, p2 = fu*cl, p3 = fu*cu;
        float fcl = min4c(p0, p1, p2, p3);
        float fcu = max4c(p0, p1, p2, p3);
        p0 = il*gl_; p1 = il*gu_; p2 = iu*gl_; p3 = iu*gu_;
        float igl = min4c(p0, p1, p2, p3);
        float igu = max4c(p0, p1, p2, p3);
        cl = fcl + igl; cu = fcu + igu;
        float tl = tanh_f(cl), tu = tanh_f(cu);
        p0 = ol*tl; p1 = ol*tu; p2 = ou*tl; p3 = ou*tu;
        float hl = min4c(p0, p1, p2, p3);
        float hu = max4c(p0, p1, p2, p3);
        hl_p = hl; hu_p = hu;
        sH[0][t >> 6][t & 63] = __float2half(0.5f * (hl + hu));
        sH[1][t >> 6][t & 63] = __float2half(0.5f * (hu - hl));
      }
      __syncthreads();
      plu = nlu;
    }
    if (t < NH) {
      size_t o = (size_t)(NT - 1) * NH + t;
      outb[OSTRIDE + o] = hl_p; outb[2 * OSTRIDE + o] = hu_p;
    }
  }
}

extern "C" void kernel_launch(void* const* d_in, const int* in_sizes, int n_in,
                              void* d_out, int out_size, void* d_ws, size_t ws_size,
                              hipStream_t stream) {
  const float* xv   = (const float*)d_in[0];
  const float* xl   = (const float*)d_in[1];
  const float* xu   = (const float*)d_in[2];
  const float* Wih  = (const float*)d_in[3];
  const float* Whh  = (const float*)d_in[4];
  const float* bias = (const float*)d_in[5];
  float* out = (float*)d_out;
  char* ws = (char*)d_ws;
  uint4*  P4  = (uint4*)ws;                    // 512 KiB (recurrent W, 4-row layout)
  uint4*  PIH = (uint4*)(ws + 512 * 1024);     // 256 KiB (px weights)
  __half* px  = (__half*)(ws + 768 * 1024);    // 192 MiB (val G4 + intv 2*G4 interleaved)

  conv_w_kernel<<<192, 256, 0, stream>>>(Whh, Wih, P4, PIH);
  px_kernel<<<NBT / 32, 512, 0, stream>>>(xv, xl, xu, PIH, bias, px);
  lstm_kernel<<<2 * NB, 1024, 0, stream>>>(P4, px, out);
}